// Round 6
// baseline (26.097 us; speedup 1.0000x reference)
//
#include <hip/hip_runtime.h>

#define LN 8192           // 8194 - 2
#define B_ROWS 4096
#define NMEANS 6

#define COLS_PER_BLOCK 1024   // 256 threads * 4 floats
#define ROWS_PER_BLOCK 16
#define COL_SEGS (LN / COLS_PER_BLOCK)        // 8
#define ROW_CHUNKS (B_ROWS / ROWS_PER_BLOCK)  // 256

typedef float v4f __attribute__((ext_vector_type(4)));

// ---------------------------------------------------------------------------
// row[j] = sum_k w_k * exp(-0.5*((pos-0.2k)/0.2)^2) * norm,  pos = j/8192.
// With u = 5*pos:  exp(-0.5*(u-k)^2) = exp(-0.5u^2) * (e^u)^k * e^(-0.5k^2)
// => row = exp(-0.5u^2) * Horner_k( w_k * norm * e^(-0.5k^2), E=e^u )
// Only TWO v_exp_f32 per element instead of six (quarter-rate trans pipe is
// the serialized prologue before the store stream starts).
// ---------------------------------------------------------------------------
__global__ void __launch_bounds__(256)
fused_kernel(const float* __restrict__ w, float* __restrict__ out) {
    const int bid     = blockIdx.x;
    const int colSeg  = bid & (COL_SEGS - 1);        // 0..7
    const int rowBase = (bid >> 3) * ROWS_PER_BLOCK; // 0..4080 step 16

    const int j0 = colSeg * COLS_PER_BLOCK + threadIdx.x * 4;

    // norm * exp(-0.5*k^2), k = 0..5  (norm = 1/(0.2*sqrt(2*pi)))
    const float bk[NMEANS] = {1.99471140f, 1.20985428f, 0.26995483f,
                              0.02215925f, 6.69151e-4f, 7.43360e-6f};
    float a[NMEANS];
#pragma unroll
    for (int k = 0; k < NMEANS; ++k) a[k] = w[k] * bk[k];

    v4f v;
#pragma unroll
    for (int e = 0; e < 4; ++e) {
        float u = (float)(j0 + e) * (5.0f / (float)LN);  // 5 * pos
        float g = __expf(-0.5f * u * u);
        float E = __expf(u);
        float h = a[5];
        h = h * E + a[4];
        h = h * E + a[3];
        h = h * E + a[2];
        h = h * E + a[1];
        h = h * E + a[0];
        v[e] = g * h;
    }

    // stream the tile: 16 rows, fully-coalesced 1 KiB/wave plain stores
    float* base = out + (long long)rowBase * LN + j0;
#pragma unroll
    for (int r = 0; r < ROWS_PER_BLOCK; ++r) {
        *(v4f*)(base + (long long)r * LN) = v;
    }
}

extern "C" void kernel_launch(void* const* d_in, const int* in_sizes, int n_in,
                              void* d_out, int out_size, void* d_ws, size_t ws_size,
                              hipStream_t stream) {
    const float* w = (const float*)d_in[0];   // weights [6]
    // d_in[1] (inp) is shape-only in the reference -> never read.
    float* out = (float*)d_out;

    fused_kernel<<<dim3(COL_SEGS * ROW_CHUNKS), dim3(256), 0, stream>>>(w, out);
}